// Round 8
// baseline (388.433 us; speedup 1.0000x reference)
//
#include <hip/hip_runtime.h>
#include <hip/hip_bf16.h>

// GCN 2-layer, fp32 I/O. Pipeline per layer:
//   gemm (register-tiled) -> bin_count + scan_small (bucket totals -> base/cursor)
//        -> bin_scatter (LDS counting sort by dst>>8, atomic run reservation, coalesced writes)
//        -> bucket_sort (in-LDS counting sort by dst&255 -> dst-sorted recs + rowptr)
//        -> gather (2 nodes/wave, packed bf16x2, 8 outstanding gathers)
// h1 kept bf16 (12.8 MB table ~L2-resident). Record int2: .x = src | (dst&255)<<20, .y = w bits.

#define EPB 4096     // edges per binning block
#define NBMAX 512    // max buckets (N <= 131072)
#define CAP 6144     // max records per bucket (avg 4096; 32-sigma headroom)

// ---------------- dense layers (register-tiled, k-major LDS) ----------------

// gemm1: [N,128] @ [128,64] -> bf16 [N,64]. 128 threads, tile 128n x 64f, thread 8x8.
__global__ __launch_bounds__(128) void gemm1_kernel(const float* __restrict__ x,
                                                    const float* __restrict__ W1,
                                                    __hip_bfloat16* __restrict__ h1,
                                                    int n_nodes) {
    __shared__ float As[32][132];
    __shared__ float Bs[32][64];
    int tid = threadIdx.x;
    int node0 = blockIdx.x * 128;
    int n8 = (tid & 15) * 8;
    int f8 = (tid >> 4) * 8;
    float acc[8][8];
#pragma unroll
    for (int i = 0; i < 8; ++i)
#pragma unroll
        for (int j = 0; j < 8; ++j) acc[i][j] = 0.f;

    const float4* x4 = reinterpret_cast<const float4*>(x);
    const float4* W4 = reinterpret_cast<const float4*>(W1);

    for (int s = 0; s < 4; ++s) {
#pragma unroll
        for (int j = 0; j < 8; ++j) {
            int idx = tid + j * 128;
            int n = idx >> 3;
            int kq = idx & 7;
            float4 v = make_float4(0.f, 0.f, 0.f, 0.f);
            if (node0 + n < n_nodes) v = x4[(size_t)(node0 + n) * 32 + s * 8 + kq];
            int k4 = kq * 4;
            As[k4 + 0][n] = v.x;
            As[k4 + 1][n] = v.y;
            As[k4 + 2][n] = v.z;
            As[k4 + 3][n] = v.w;
        }
#pragma unroll
        for (int j = 0; j < 4; ++j) {
            int idx = tid + j * 128;
            int k = idx >> 4;
            int fq = idx & 15;
            *reinterpret_cast<float4*>(&Bs[k][fq * 4]) = W4[(size_t)(s * 32 + k) * 16 + fq];
        }
        __syncthreads();
#pragma unroll
        for (int kk = 0; kk < 32; ++kk) {
            float4 a0 = *reinterpret_cast<const float4*>(&As[kk][n8]);
            float4 a1 = *reinterpret_cast<const float4*>(&As[kk][n8 + 4]);
            float4 b0 = *reinterpret_cast<const float4*>(&Bs[kk][f8]);
            float4 b1 = *reinterpret_cast<const float4*>(&Bs[kk][f8 + 4]);
            float av[8] = {a0.x, a0.y, a0.z, a0.w, a1.x, a1.y, a1.z, a1.w};
            float bv[8] = {b0.x, b0.y, b0.z, b0.w, b1.x, b1.y, b1.z, b1.w};
#pragma unroll
            for (int i = 0; i < 8; ++i)
#pragma unroll
                for (int j = 0; j < 8; ++j) acc[i][j] += av[i] * bv[j];
        }
        __syncthreads();
    }
#pragma unroll
    for (int i = 0; i < 8; ++i) {
        int n = node0 + n8 + i;
        if (n < n_nodes) {
            __hip_bfloat16 tmp[8];
#pragma unroll
            for (int j = 0; j < 8; ++j) tmp[j] = __float2bfloat16(acc[i][j]);
            *reinterpret_cast<uint4*>(&h1[(size_t)n * 64 + f8]) =
                *reinterpret_cast<const uint4*>(tmp);
        }
    }
}

// gemm2: [N,64] @ [64,16] -> fp32 [N,16]. 128 threads, tile 128n x 16f, thread 4x4.
__global__ __launch_bounds__(128) void gemm2_kernel(const float* __restrict__ agg1,
                                                    const float* __restrict__ W2,
                                                    float* __restrict__ h2, int n_nodes) {
    __shared__ float As[32][132];
    __shared__ float Bs[32][16];
    int tid = threadIdx.x;
    int node0 = blockIdx.x * 128;
    int n4 = (tid & 31) * 4;
    int f4 = (tid >> 5) * 4;
    float acc[4][4];
#pragma unroll
    for (int i = 0; i < 4; ++i)
#pragma unroll
        for (int j = 0; j < 4; ++j) acc[i][j] = 0.f;

    const float4* a4 = reinterpret_cast<const float4*>(agg1);
    const float4* W4 = reinterpret_cast<const float4*>(W2);

    for (int s = 0; s < 2; ++s) {
#pragma unroll
        for (int j = 0; j < 8; ++j) {
            int idx = tid + j * 128;
            int n = idx >> 3;
            int kq = idx & 7;
            float4 v = make_float4(0.f, 0.f, 0.f, 0.f);
            if (node0 + n < n_nodes) v = a4[(size_t)(node0 + n) * 16 + s * 8 + kq];
            int k4 = kq * 4;
            As[k4 + 0][n] = v.x;
            As[k4 + 1][n] = v.y;
            As[k4 + 2][n] = v.z;
            As[k4 + 3][n] = v.w;
        }
        {
            int k = tid >> 2, fq = tid & 3;
            *reinterpret_cast<float4*>(&Bs[k][fq * 4]) = W4[(size_t)(s * 32 + k) * 4 + fq];
        }
        __syncthreads();
#pragma unroll
        for (int kk = 0; kk < 32; ++kk) {
            float4 a = *reinterpret_cast<const float4*>(&As[kk][n4]);
            float4 b = *reinterpret_cast<const float4*>(&Bs[kk][f4]);
            float av[4] = {a.x, a.y, a.z, a.w};
            float bv[4] = {b.x, b.y, b.z, b.w};
#pragma unroll
            for (int i = 0; i < 4; ++i)
#pragma unroll
                for (int j = 0; j < 4; ++j) acc[i][j] += av[i] * bv[j];
        }
        __syncthreads();
    }
#pragma unroll
    for (int i = 0; i < 4; ++i) {
        int n = node0 + n4 + i;
        if (n < n_nodes)
            *reinterpret_cast<float4*>(h2 + (size_t)n * 16 + f4) =
                make_float4(acc[i][0], acc[i][1], acc[i][2], acc[i][3]);
    }
}

// ---------------- binning: bucket totals -> base/cursor -> atomic-reserved runs ----------------

__global__ void bin_count_kernel(const int* __restrict__ ei, int* __restrict__ bucket_total,
                                 int n_edges, int nb) {
    __shared__ int hist[NBMAX];
    int tid = threadIdx.x, blk = blockIdx.x;
    for (int i = tid; i < nb; i += 256) hist[i] = 0;
    __syncthreads();
    int e0 = blk * EPB;
#pragma unroll
    for (int j = 0; j < EPB / 256; ++j) {
        int e = e0 + tid + j * 256;
        if (e < n_edges) atomicAdd(&hist[ei[n_edges + e] >> 8], 1);
    }
    __syncthreads();
    for (int i = tid; i < nb; i += 256)
        if (hist[i] > 0) atomicAdd(&bucket_total[i], hist[i]);
}

// single block: exclusive scan of bucket_total[0..nb) -> bucket_base, cursor
__global__ __launch_bounds__(512) void scan_small_kernel(const int* __restrict__ bucket_total,
                                                         int* __restrict__ bucket_base,
                                                         int* __restrict__ cursor, int nb) {
    __shared__ int tmp[512];
    int tid = threadIdx.x;
    int v = (tid < nb) ? bucket_total[tid] : 0;
    tmp[tid] = v;
    __syncthreads();
    for (int off = 1; off < 512; off <<= 1) {
        int t = (tid >= off) ? tmp[tid - off] : 0;
        __syncthreads();
        tmp[tid] += t;
        __syncthreads();
    }
    if (tid < nb) {
        int excl = tmp[tid] - v;
        bucket_base[tid] = excl;
        cursor[tid] = excl;
    }
    if (tid == 0) bucket_base[nb] = tmp[511];   // == n_edges
}

__global__ void bin_scatter_kernel(const int* __restrict__ ei, const float* __restrict__ ew,
                                   int* __restrict__ cursor, int2* __restrict__ rec_out,
                                   int n_edges, int nb) {
    __shared__ int2 srec[EPB];               // 32 KB
    __shared__ unsigned short sbkt[EPB];     // 8 KB
    __shared__ int hist[NBMAX], loff[NBMAX], cur[NBMAX], gbase[NBMAX];  // 8 KB
    __shared__ int p[256];
    int tid = threadIdx.x, blk = blockIdx.x;
    int e0 = blk * EPB;
    int cnt = min(EPB, n_edges - e0);
    for (int i = tid; i < nb; i += 256) hist[i] = 0;
    __syncthreads();
#pragma unroll
    for (int j = 0; j < EPB / 256; ++j) {
        int e = e0 + tid + j * 256;
        if (e < n_edges) atomicAdd(&hist[ei[n_edges + e] >> 8], 1);
    }
    __syncthreads();
    // local exclusive scan of hist -> loff (2 buckets/thread + Hillis-Steele over partials)
    int b0 = tid * 2;
    int c0 = (b0 < nb) ? hist[b0] : 0;
    int c1 = (b0 + 1 < nb) ? hist[b0 + 1] : 0;
    p[tid] = c0 + c1;
    __syncthreads();
    for (int off = 1; off < 256; off <<= 1) {
        int t = (tid >= off) ? p[tid - off] : 0;
        __syncthreads();
        p[tid] += t;
        __syncthreads();
    }
    int base = (tid > 0) ? p[tid - 1] : 0;
    __syncthreads();
    if (b0 < nb)     { loff[b0] = base;          cur[b0] = base; }
    if (b0 + 1 < nb) { loff[b0 + 1] = base + c0; cur[b0 + 1] = base + c0; }
    // reserve global run space per bucket (order across blocks nondeterministic — harmless)
    for (int i = tid; i < nb; i += 256)
        if (hist[i] > 0) gbase[i] = atomicAdd(&cursor[i], hist[i]);
    __syncthreads();
    // rank + stage (LDS counting sort by bucket)
#pragma unroll
    for (int j = 0; j < EPB / 256; ++j) {
        int e = e0 + tid + j * 256;
        if (e < n_edges) {
            int s = ei[e], d = ei[n_edges + e];
            int b = d >> 8;
            int r = atomicAdd(&cur[b], 1);
            srec[r] = make_int2(s | ((d & 255) << 20), __float_as_int(ew[e]));
            sbkt[r] = (unsigned short)b;
        }
    }
    __syncthreads();
    // coalesced run writes
    for (int i = tid; i < cnt; i += 256) {
        int b = sbkt[i];
        rec_out[gbase[b] + (i - loff[b])] = srec[i];
    }
}

// ---------------- per-bucket node sort (-> dst-sorted recs + rowptr) ----------------

__global__ __launch_bounds__(256) void bucket_sort_kernel(
        const int2* __restrict__ rec_in, const int* __restrict__ bucket_base,
        int2* __restrict__ rec_out, int* __restrict__ rowptr,
        int n_nodes, int n_edges, int nb) {
    __shared__ int2 srec[CAP];               // 48 KB
    __shared__ int hist[256], cur[256], rp[256];
    int tid = threadIdx.x, b = blockIdx.x;
    int start = bucket_base[b];
    int end = bucket_base[b + 1];
    int cnt = end - start;
    hist[tid] = 0;
    __syncthreads();
    for (int i = tid; i < cnt; i += 256) {
        int2 r = rec_in[start + i];
        atomicAdd(&hist[(r.x >> 20) & 255], 1);
    }
    __syncthreads();
    int v = hist[tid];
    rp[tid] = v;
    __syncthreads();
    for (int off = 1; off < 256; off <<= 1) {
        int t = (tid >= off) ? rp[tid - off] : 0;
        __syncthreads();
        rp[tid] += t;
        __syncthreads();
    }
    int excl = rp[tid] - v;
    cur[tid] = excl;
    int node = (b << 8) + tid;
    if (node < n_nodes) rowptr[node] = start + excl;
    if (b == nb - 1 && tid == 0) rowptr[n_nodes] = n_edges;
    __syncthreads();
    for (int i = tid; i < cnt; i += 256) {
        int2 r = rec_in[start + i];
        int rk = atomicAdd(&cur[(r.x >> 20) & 255], 1);
        if (rk < CAP) srec[rk] = r;
    }
    __syncthreads();
    int lim = min(cnt, CAP);
    for (int i = tid; i < lim; i += 256) rec_out[start + i] = srec[i];
}

// ---------------- gather-side aggregation ----------------

// 2 nodes per wave (32 lanes each), lane reads uint = 2 packed bf16 feats.
// 4-wide ILP per node => 8 independent gathers in flight per wave.
__global__ void gather1_kernel(const __hip_bfloat16* __restrict__ h1,
                               const int* __restrict__ rowptr,
                               const int2* __restrict__ rec,
                               float* __restrict__ agg, int n_nodes) {
    int wave = threadIdx.x >> 6;
    int lane = threadIdx.x & 63;
    int half = lane >> 5;
    int fl = lane & 31;                      // feat-pair index: feats 2*fl, 2*fl+1
    int n = blockIdx.x * 8 + wave * 2 + half;
    if (n >= n_nodes) return;
    const unsigned int* h1u = reinterpret_cast<const unsigned int*>(h1);
    int i = rowptr[n], end = rowptr[n + 1];
    float a0 = 0.f, b0 = 0.f, a1 = 0.f, b1 = 0.f;
    for (; i + 3 < end; i += 4) {
        int2 r0 = rec[i], r1 = rec[i + 1], r2 = rec[i + 2], r3 = rec[i + 3];
        unsigned int v0 = h1u[(size_t)(r0.x & 0xFFFFF) * 32 + fl];
        unsigned int v1 = h1u[(size_t)(r1.x & 0xFFFFF) * 32 + fl];
        unsigned int v2 = h1u[(size_t)(r2.x & 0xFFFFF) * 32 + fl];
        unsigned int v3 = h1u[(size_t)(r3.x & 0xFFFFF) * 32 + fl];
        float w0 = __int_as_float(r0.y), w1 = __int_as_float(r1.y);
        float w2 = __int_as_float(r2.y), w3 = __int_as_float(r3.y);
        a0 += __uint_as_float(v0 << 16) * w0;  b0 += __uint_as_float(v0 & 0xFFFF0000u) * w0;
        a1 += __uint_as_float(v1 << 16) * w1;  b1 += __uint_as_float(v1 & 0xFFFF0000u) * w1;
        a0 += __uint_as_float(v2 << 16) * w2;  b0 += __uint_as_float(v2 & 0xFFFF0000u) * w2;
        a1 += __uint_as_float(v3 << 16) * w3;  b1 += __uint_as_float(v3 & 0xFFFF0000u) * w3;
    }
    for (; i < end; ++i) {
        int2 r = rec[i];
        unsigned int v = h1u[(size_t)(r.x & 0xFFFFF) * 32 + fl];
        float w = __int_as_float(r.y);
        a0 += __uint_as_float(v << 16) * w;    b0 += __uint_as_float(v & 0xFFFF0000u) * w;
    }
    float2 st = make_float2(fmaxf(a0 + a1, 0.f), fmaxf(b0 + b1, 0.f));  // fused relu
    *reinterpret_cast<float2*>(&agg[(size_t)n * 64 + 2 * fl]) = st;
}

__global__ void gather2_kernel(const float* __restrict__ h2,
                               const int* __restrict__ rowptr,
                               const int2* __restrict__ rec,
                               float* __restrict__ out, int n_nodes) {
    int n = blockIdx.x * 16 + (threadIdx.x >> 4);
    if (n >= n_nodes) return;
    int f = threadIdx.x & 15;
    int i = rowptr[n], end = rowptr[n + 1];
    float a0 = 0.f, a1 = 0.f, a2 = 0.f, a3 = 0.f;
    for (; i + 3 < end; i += 4) {
        int2 r0 = rec[i], r1 = rec[i + 1], r2 = rec[i + 2], r3 = rec[i + 3];
        a0 += h2[(size_t)(r0.x & 0xFFFFF) * 16 + f] * __int_as_float(r0.y);
        a1 += h2[(size_t)(r1.x & 0xFFFFF) * 16 + f] * __int_as_float(r1.y);
        a2 += h2[(size_t)(r2.x & 0xFFFFF) * 16 + f] * __int_as_float(r2.y);
        a3 += h2[(size_t)(r3.x & 0xFFFFF) * 16 + f] * __int_as_float(r3.y);
    }
    for (; i < end; ++i) {
        int2 r = rec[i];
        a0 += h2[(size_t)(r.x & 0xFFFFF) * 16 + f] * __int_as_float(r.y);
    }
    out[(size_t)n * 16 + f] = (a0 + a1) + (a2 + a3);
}

// ---------------- launch ----------------

extern "C" void kernel_launch(void* const* d_in, const int* in_sizes, int n_in,
                              void* d_out, int out_size, void* d_ws, size_t ws_size,
                              hipStream_t stream) {
    const float* x   = (const float*)d_in[0];
    const int*   ei1 = (const int*)d_in[1];
    const int*   ei2 = (const int*)d_in[2];
    const float* ew1 = (const float*)d_in[3];
    const float* ew2 = (const float*)d_in[4];
    const float* W1  = (const float*)d_in[5];
    const float* W2  = (const float*)d_in[6];

    const int n_nodes = in_sizes[0] / 128;          // 100000
    const int n_edges = in_sizes[1] / 2;            // 1600000
    const int nb   = (n_nodes + 255) >> 8;          // 391 buckets
    const int nblk = (n_edges + EPB - 1) / EPB;     // 391 binning blocks

    // ws layout (4-byte units)
    __hip_bfloat16* h1 = (__hip_bfloat16*)d_ws;          // N*64 bf16 = N*32 floats
    float* agg1   = (float*)d_ws + (size_t)n_nodes * 32; // N*64
    float* h2     = agg1 + (size_t)n_nodes * 64;         // N*16
    int2*  recbuf = (int2*)(h2 + (size_t)n_nodes * 16);  // E int2 (bucket-sorted)
    int2*  rec2   = recbuf + n_edges;                    // E int2 (node-sorted)
    int*   btotal = (int*)(rec2 + n_edges);              // nb
    int*   bbase  = btotal + nb;                         // nb+1
    int*   cursor = bbase + nb + 1;                      // nb
    int*   rowptr = cursor + nb;                         // N+1
    float* out    = (float*)d_out;

    // ---- layer 1 ----
    gemm1_kernel<<<(n_nodes + 127) / 128, 128, 0, stream>>>(x, W1, h1, n_nodes);
    hipMemsetAsync(btotal, 0, nb * sizeof(int), stream);
    bin_count_kernel<<<nblk, 256, 0, stream>>>(ei1, btotal, n_edges, nb);
    scan_small_kernel<<<1, 512, 0, stream>>>(btotal, bbase, cursor, nb);
    bin_scatter_kernel<<<nblk, 256, 0, stream>>>(ei1, ew1, cursor, recbuf, n_edges, nb);
    bucket_sort_kernel<<<nb, 256, 0, stream>>>(recbuf, bbase, rec2, rowptr,
                                               n_nodes, n_edges, nb);
    gather1_kernel<<<(n_nodes + 7) / 8, 256, 0, stream>>>(h1, rowptr, rec2, agg1, n_nodes);

    // ---- layer 2 ----
    gemm2_kernel<<<(n_nodes + 127) / 128, 128, 0, stream>>>(agg1, W2, h2, n_nodes);
    hipMemsetAsync(btotal, 0, nb * sizeof(int), stream);
    bin_count_kernel<<<nblk, 256, 0, stream>>>(ei2, btotal, n_edges, nb);
    scan_small_kernel<<<1, 512, 0, stream>>>(btotal, bbase, cursor, nb);
    bin_scatter_kernel<<<nblk, 256, 0, stream>>>(ei2, ew2, cursor, recbuf, n_edges, nb);
    bucket_sort_kernel<<<nb, 256, 0, stream>>>(recbuf, bbase, rec2, rowptr,
                                               n_nodes, n_edges, nb);
    gather2_kernel<<<(n_nodes + 15) / 16, 256, 0, stream>>>(h2, rowptr, rec2, out, n_nodes);
}